// Round 9
// baseline (112.784 us; speedup 1.0000x reference)
//
#include <hip/hip_runtime.h>
#include <hip/hip_bf16.h>
#include <stdint.h>

// Problem constants
#define BATCH 16
#define IN_CH 64
#define HIN 56
#define WIN_ 56
#define HO 54
#define WO 54
#define P_PER_B (HO*WO)        // 2916
#define P_PAD 2944             // 23 * 128
#define OUT_CH 256
#define KDIM 576               // 64*3*3
#define NPIX (HIN*WIN_)        // 3136
#define XT_PIX 3264            // padded pixel rows per batch (A-region staging overrun)

typedef __attribute__((ext_vector_type(8))) short short8;
typedef __attribute__((ext_vector_type(4))) float f32x4;

__device__ __forceinline__ unsigned short f2bf(float f) {
    unsigned int u = __float_as_uint(f);
    unsigned int r = (u + 0x7fffu + ((u >> 16) & 1u)) >> 16;   // RNE
    return (unsigned short)r;
}

// ---------------- prep kernels ----------------

// One wave per output channel: bf16-convert weight row into TAP-MAJOR layout
// wbf[tap][o][c] (tap = kh*3+kw); compute ||w_o||^2 in fp32.
__global__ void prep_weight(const float* __restrict__ w, short* __restrict__ wbf,
                            float* __restrict__ c2) {
    int o = blockIdx.x;
    int lane = threadIdx.x;           // 0..63
    float s = 0.f;
    #pragma unroll
    for (int j = 0; j < 9; ++j) {     // 576 = 9*64
        int k = j * 64 + lane;        // original k = c*9 + tap
        int c = k / 9, tap = k % 9;
        float v = w[o * KDIM + k];
        s += v * v;
        ((unsigned short*)wbf)[((size_t)tap * OUT_CH + o) * 64 + c] = f2bf(v);
    }
    #pragma unroll
    for (int off = 32; off > 0; off >>= 1) s += __shfl_down(s, off);
    if (lane == 0) c2[o] = s;
}

// NCHW fp32 -> NHWC bf16 transpose (64 pix x 64 ch per block) + fused per-pixel
// channel square-sum s[b, pix]. xT row stride padded to XT_PIX pixels per batch.
__global__ __launch_bounds__(256) void transpose_kernel(
    const float* __restrict__ x, short* __restrict__ xT, float* __restrict__ s) {
    __shared__ short lds[64 * 65];
    __shared__ float red[256];
    const int b    = blockIdx.x / 49;
    const int pix0 = (blockIdx.x % 49) * 64;
    const int tid  = threadIdx.x;
    const int quarter = tid >> 6;
    const int pix  = tid & 63;
    const float* xb = x + (size_t)b * IN_CH * NPIX + pix0 + pix;
    float acc = 0.f;
    #pragma unroll
    for (int it = 0; it < 16; ++it) {
        int c = quarter * 16 + it;
        float v = xb[c * NPIX];               // wave reads 256B contiguous
        acc += v * v;
        lds[pix * 65 + c] = (short)f2bf(v);
    }
    red[tid] = acc;
    __syncthreads();
    const int cs = tid & 63;
    short* xTb = xT + ((size_t)b * XT_PIX + pix0) * 64;
    #pragma unroll
    for (int it = 0; it < 16; ++it) {
        int pixs = quarter * 16 + it;
        xTb[(size_t)pixs * 64 + cs] = lds[pixs * 65 + cs];  // wave writes 128B contiguous
    }
    if (tid < 64)
        s[b * NPIX + pix0 + tid] = red[tid] + red[64 + tid] + red[128 + tid] + red[192 + tid];
}

// w2[b*P_PAD + p] = 3x3 window sum of s  (= ||win_p||^2, fp32)
__global__ void w2_kernel(const float* __restrict__ s, float* __restrict__ w2) {
    int t = blockIdx.x * 256 + threadIdx.x;
    if (t >= BATCH * P_PER_B) return;
    int b = t / P_PER_B, p = t % P_PER_B;
    int oh = p / WO, ow = p % WO;
    const float* sp = s + b * NPIX + oh * WIN_ + ow;
    float acc = 0.f;
    #pragma unroll
    for (int kh = 0; kh < 3; ++kh)
        #pragma unroll
        for (int kw = 0; kw < 3; ++kw)
            acc += sp[kh * WIN_ + kw];
    w2[b * P_PAD + p] = acc;
}

// ---------------- fused im2col GEMM + RBF epilogue ----------------
// Block-phase redesign: gemm time was invariant (~44us) across 5 different
// K-loop schedules with all pipes ~10-25% busy -> cost is the block's ENDS
// (A-stage burst + epilogue store drain) plus chip-wide phase locking and a
// 1.44-round scheduling tail (736 blocks / 512 slots), not the tap schedule.
// Now: ONE block per m-tile handles BOTH n-tiles (all 256 channels):
//  * grid 368 <= 512 slots: all blocks resident from t=0, zero tail.
//  * A staged ONCE per m-tile (was twice).
//  * nt=0's epilogue (stores + exp) runs while nt=1's B tap0 prefetch is in
//    flight; nt=0's store DRAIN overlaps nt=1's whole K-loop.
//  * raw barriers + counted vmcnt only -> stores never force-drained.
//  * XCD-chunked swizzle (368 = 8*46): consecutive m-tiles (overlapping A
//    regions) share an XCD L2.

#define AS1(p) ((const __attribute__((address_space(1))) void*)(p))
#define AS3(p) ((__attribute__((address_space(3))) void*)(p))

__global__ __launch_bounds__(512, 4) void gemm_rbf(
    const short* __restrict__ xT, const short* __restrict__ wbf,
    const float* __restrict__ w2, const float* __restrict__ c2,
    float* __restrict__ out) {
    __shared__ __align__(16) short lds_a[352 * 64];      // 45 KB pixel region, swizzled
    __shared__ __align__(16) short lds_b[2 * 128 * 64];  // 2 x 16 KB per-tap B tiles

    const int bid = blockIdx.x;                // 0..367
    const int mt  = (bid & 7) * 46 + (bid >> 3);   // XCD-chunked, bijective (368=8*46)
    const int b   = mt / 23;
    const int p0  = (mt % 23) * 128;

    const int tid  = threadIdx.x;              // 0..511
    const int wave = tid >> 6;                 // 0..7
    const int lane = tid & 63;
    const int r16  = lane & 15;
    const int quad = lane >> 4;
    const int wm = (wave >> 2) * 64;           // 0 or 64
    const int wn = (wave & 3) * 32;            // 0,32,64,96

    const int oh_base  = p0 / WO;
    const int ihw_base = oh_base * WIN_;

    // staging lane mapping: 8 lanes per 128-B row, 16 B per lane.
    // physical chunk (lane&7) of lds row r holds logical chunk (lane&7)^(r&7).
    const int srow = lane >> 3;                // 0..7
    const int scx  = (lane & 7) ^ srow;        // pre-swizzled source chunk

    // ---- A-region staging (ONCE): 352 rows from xT, contiguous pixels ----
    const short* aSrc = xT + ((size_t)b * XT_PIX + ihw_base + srow) * 64 + scx * 8;
    #pragma unroll
    for (int i = 0; i < 6; ++i) {              // 8 waves x 6 x 8 rows, guard at 352
        int rb8 = (wave * 6 + i) * 8;
        if (rb8 < 352)
            __builtin_amdgcn_global_load_lds(AS1(aSrc + (size_t)rb8 * 64),
                                             AS3(lds_a + rb8 * 64), 16, 0, 0);
    }
    // ---- B staging bases (tap-major wbf [tap][o][c]), one per n-tile ----
    const short* gbB0 = wbf + ((size_t)(wave * 16 + srow)) * 64 + scx * 8;       // n0=0
    const short* gbB1 = gbB0 + (size_t)128 * 64;                                 // n0=128
    #pragma unroll
    for (int i = 0; i < 2; ++i)                // nt=0 tap 0 into buffer 0
        __builtin_amdgcn_global_load_lds(AS1(gbB0 + (size_t)i * 8 * 64),
                                         AS3(lds_b + (wave * 2 + i) * 512), 16, 0, 0);

    // per-fragment-row pixel index relative to the staged region (pad rows clamped;
    // their D rows are discarded in the store phase)
    int ihw_rel[4];
    #pragma unroll
    for (int ms = 0; ms < 4; ++ms) {
        int p = p0 + wm + ms * 16 + r16;
        if (p > P_PER_B - 1) p = P_PER_B - 1;
        int oh = p / WO, ow = p - oh * WO;
        ihw_rel[ms] = oh * WIN_ + ow - ihw_base;   // 0..221
    }
    const int xq = r16 & 7;                    // B fragment-read swizzle key

    // epilogue constants (shared by both n-tiles)
    const int ecol = tid & 31;                 // f32x4 column within 512-B run
    const int erow = tid >> 5;                 // 0..15
    const int pcol = p0 + ecol * 4;
    const bool pok = (pcol < P_PER_B);         // aligned: P_PER_B % 4 == 0
    f32x4 w2v = *(const f32x4*)(w2 + b * P_PAD + pcol);  // pad region valid mem

    __syncthreads();                           // A region + B(nt0,tap0) resident

    constexpr int dtab_l[9] = {0, 1, 2, 56, 57, 58, 112, 113, 114};  // kh*56+kw
    #pragma unroll
    for (int nt = 0; nt < 2; ++nt) {
        const short* gB = (nt == 0) ? gbB0 : gbB1;

        f32x4 acc[4][2];
        #pragma unroll
        for (int i = 0; i < 4; ++i)
            #pragma unroll
            for (int j = 0; j < 2; ++j)
                acc[i][j] = (f32x4){0.f, 0.f, 0.f, 0.f};

        #pragma unroll
        for (int kt = 0; kt < 9; ++kt) {
            // counted wait: at nt=1/kt=0 the needed B loads were issued BEFORE
            // the 8 per-wave epilogue stores of nt=0; in-order vmcnt retirement
            // means <=8 outstanding implies those loads landed -> stores are
            // NOT drained here. Elsewhere vmcnt(0) (loads issued one tap ago).
            if (nt == 1 && kt == 0)
                asm volatile("s_waitcnt vmcnt(8)" ::: "memory");
            else
                asm volatile("s_waitcnt vmcnt(0)" ::: "memory");
            __builtin_amdgcn_s_barrier();
            __builtin_amdgcn_sched_barrier(0);
            if (kt < 8) {                      // issue next tap's B under MFMA
                short* dstB = lds_b + ((kt + 1) & 1) * (128 * 64);
                #pragma unroll
                for (int i = 0; i < 2; ++i)
                    __builtin_amdgcn_global_load_lds(
                        AS1(gB + ((size_t)(kt + 1) * OUT_CH + i * 8) * 64),
                        AS3(dstB + (wave * 2 + i) * 512), 16, 0, 0);
            }
            const short* lb = lds_b + (kt & 1) * (128 * 64);
            const int dt = dtab_l[kt];
            __builtin_amdgcn_s_setprio(1);
            #pragma unroll
            for (int ks = 0; ks < 2; ++ks) {
                short8 af[4], bfr[2];
                #pragma unroll
                for (int ms = 0; ms < 4; ++ms) {
                    int rl = ihw_rel[ms] + dt; // staged-region row for this tap
                    af[ms] = *(const short8*)(lds_a + rl * 64
                                                    + (((ks * 4 + quad) ^ (rl & 7)) * 8));
                }
                #pragma unroll
                for (int ns = 0; ns < 2; ++ns)
                    bfr[ns] = *(const short8*)(lb + (wn + ns * 16 + r16) * 64
                                                  + (((ks * 4 + quad) ^ xq) * 8));
                #pragma unroll
                for (int ms = 0; ms < 4; ++ms)
                    #pragma unroll
                    for (int ns = 0; ns < 2; ++ns)
                        acc[ms][ns] = __builtin_amdgcn_mfma_f32_16x16x32_bf16(
                            af[ms], bfr[ns], acc[ms][ns], 0, 0, 0);
            }
            __builtin_amdgcn_s_setprio(0);
        }

        // all waves' tap-8 LDS reads are consumed (per-wave lgkmcnt before
        // MFMAs) by the time they pass this barrier -> LDS reusable.
        __builtin_amdgcn_s_barrier();
        __builtin_amdgcn_sched_barrier(0);

        if (nt == 0) {
            // prefetch B(nt=1, tap0) into buf0 FIRST (oldest VMEM before the
            // epilogue stores -> enables the vmcnt(8) wait above)
            #pragma unroll
            for (int i = 0; i < 2; ++i)
                __builtin_amdgcn_global_load_lds(AS1(gbB1 + (size_t)i * 8 * 64),
                                                 AS3(lds_b + (wave * 2 + i) * 512), 16, 0, 0);
            // coalesced RBF epilogue for channels [0,128): 8 chunks of 16 ch
            // via buf1 (16 KB) as [16][132] f32 transpose tile.
            float* lf = (float*)(lds_b + 128 * 64);
            #pragma unroll
            for (int c = 0; c < 8; ++c) {
                if ((wave & 3) == (c >> 1)) {  // owner waves (2) dump acc
                    const int ns = c & 1;
                    #pragma unroll
                    for (int ms = 0; ms < 4; ++ms)
                        *(f32x4*)(lf + r16 * 132 + wm + ms * 16 + quad * 4) = acc[ms][ns];
                }
                asm volatile("s_waitcnt lgkmcnt(0)" ::: "memory");
                __builtin_amdgcn_s_barrier();
                __builtin_amdgcn_sched_barrier(0);
                {
                    int o = c * 16 + erow;     // n0 = 0
                    f32x4 a = *(const f32x4*)(lf + erow * 132 + ecol * 4);
                    float c2o = c2[o];
                    f32x4 v;
                    #pragma unroll
                    for (int r = 0; r < 4; ++r) {
                        float d2 = w2v[r] + c2o - 2.0f * a[r];
                        d2 = fmaxf(d2, 1e-12f);
                        v[r] = __expf(-0.125f * d2);
                    }
                    if (pok)
                        *(f32x4*)(out + ((size_t)(b * OUT_CH + o)) * P_PER_B + pcol) = v;
                }
                __builtin_amdgcn_s_barrier();  // readers done before next writers
                __builtin_amdgcn_sched_barrier(0);
            }
        } else {
            // channels [128,256): lds_a is free now -> [64][132] f32, 2 chunks
            float* lf = (float*)lds_a;
            #pragma unroll
            for (int s = 0; s < 2; ++s) {
                if (((wave >> 1) & 1) == s) {
                    #pragma unroll
                    for (int ms = 0; ms < 4; ++ms) {
                        int pl = wm + ms * 16 + quad * 4;
                        #pragma unroll
                        for (int ns = 0; ns < 2; ++ns) {
                            int od = (wave & 1) * 32 + ns * 16 + r16;
                            *(f32x4*)(lf + od * 132 + pl) = acc[ms][ns];
                        }
                    }
                }
                asm volatile("s_waitcnt lgkmcnt(0)" ::: "memory");
                __builtin_amdgcn_s_barrier();
                __builtin_amdgcn_sched_barrier(0);
                #pragma unroll
                for (int pass = 0; pass < 4; ++pass) {
                    int row = pass * 16 + erow;
                    int o   = 128 + s * 64 + row;
                    f32x4 a = *(const f32x4*)(lf + row * 132 + ecol * 4);
                    float c2o = c2[o];
                    f32x4 v;
                    #pragma unroll
                    for (int r = 0; r < 4; ++r) {
                        float d2 = w2v[r] + c2o - 2.0f * a[r];
                        d2 = fmaxf(d2, 1e-12f);
                        v[r] = __expf(-0.125f * d2);
                    }
                    if (pok)
                        *(f32x4*)(out + ((size_t)(b * OUT_CH + o)) * P_PER_B + pcol) = v;
                }
                __builtin_amdgcn_s_barrier();
                __builtin_amdgcn_sched_barrier(0);
            }
        }
    }
}

// ---------------- launch ----------------

extern "C" void kernel_launch(void* const* d_in, const int* in_sizes, int n_in,
                              void* d_out, int out_size, void* d_ws, size_t ws_size,
                              hipStream_t stream) {
    const float* x = (const float*)d_in[0];    // [16,64,56,56]
    const float* w = (const float*)d_in[1];    // [256,576]
    float* out = (float*)d_out;                // [16,256,54,54]

    char* ws = (char*)d_ws;
    const size_t wbf_bytes = (size_t)OUT_CH * KDIM * 2;            // 294,912
    const size_t c2_bytes  = 1024;                                 // OUT_CH*4
    const size_t w2_bytes  = (size_t)BATCH * P_PAD * 4;            // 188,416
    const size_t s_bytes   = (size_t)BATCH * NPIX * 4;             // 200,704
    short* wbf = (short*)ws;
    float* c2  = (float*)(ws + wbf_bytes);
    float* w2  = (float*)(ws + wbf_bytes + c2_bytes);
    float* s   = (float*)(ws + wbf_bytes + c2_bytes + w2_bytes);
    short* xT  = (short*)(ws + wbf_bytes + c2_bytes + w2_bytes + s_bytes);  // 6.68 MB

    hipLaunchKernelGGL(prep_weight, dim3(OUT_CH), dim3(64), 0, stream, w, wbf, c2);
    hipLaunchKernelGGL(transpose_kernel, dim3(16 * 49), dim3(256), 0, stream, x, xT, s);
    hipLaunchKernelGGL(w2_kernel, dim3((BATCH * P_PER_B + 255) / 256), dim3(256), 0, stream, s, w2);
    hipLaunchKernelGGL(gemm_rbf, dim3(368), dim3(512), 0, stream,
                       xT, wbf, w2, c2, out);
}

// Round 10
// 103.377 us; speedup vs baseline: 1.0910x; 1.0910x over previous
//
#include <hip/hip_runtime.h>
#include <hip/hip_bf16.h>
#include <stdint.h>

// Problem constants
#define BATCH 16
#define IN_CH 64
#define HIN 56
#define WIN_ 56
#define HO 54
#define WO 54
#define P_PER_B (HO*WO)        // 2916
#define P_PAD 2944             // 23 * 128
#define OUT_CH 256
#define KDIM 576               // 64*3*3
#define NPIX (HIN*WIN_)        // 3136
#define XT_PIX 3264            // padded pixel rows per batch (A-region staging overrun)

typedef __attribute__((ext_vector_type(8))) short short8;
typedef __attribute__((ext_vector_type(4))) float f32x4;

__device__ __forceinline__ unsigned short f2bf(float f) {
    unsigned int u = __float_as_uint(f);
    unsigned int r = (u + 0x7fffu + ((u >> 16) & 1u)) >> 16;   // RNE
    return (unsigned short)r;
}

// ---------------- prep kernels ----------------

// One wave per output channel: bf16-convert weight row into TAP-MAJOR layout
// wbf[tap][o][c] (tap = kh*3+kw); compute ||w_o||^2 in fp32.
__global__ void prep_weight(const float* __restrict__ w, short* __restrict__ wbf,
                            float* __restrict__ c2) {
    int o = blockIdx.x;
    int lane = threadIdx.x;           // 0..63
    float s = 0.f;
    #pragma unroll
    for (int j = 0; j < 9; ++j) {     // 576 = 9*64
        int k = j * 64 + lane;        // original k = c*9 + tap
        int c = k / 9, tap = k % 9;
        float v = w[o * KDIM + k];
        s += v * v;
        ((unsigned short*)wbf)[((size_t)tap * OUT_CH + o) * 64 + c] = f2bf(v);
    }
    #pragma unroll
    for (int off = 32; off > 0; off >>= 1) s += __shfl_down(s, off);
    if (lane == 0) c2[o] = s;
}

// NCHW fp32 -> NHWC bf16 transpose (64 pix x 64 ch per block) + fused per-pixel
// channel square-sum s[b, pix]. float4 loads: lane covers 4 pixels -> 4x fewer
// global instrs at the same coalescing. xT row stride padded to XT_PIX.
__global__ __launch_bounds__(256) void transpose_kernel(
    const float* __restrict__ x, short* __restrict__ xT, float* __restrict__ s) {
    __shared__ short lds[64 * 65];
    __shared__ float red4[256 * 4];            // [cq][pixgrp][4]
    const int b    = blockIdx.x / 49;
    const int pix0 = (blockIdx.x % 49) * 64;
    const int tid  = threadIdx.x;
    const int cq = tid >> 4;                   // 0..15 channel group
    const int pg = tid & 15;                   // 0..15 pixel group (4 pix each)
    const float* xb = x + (size_t)b * IN_CH * NPIX + pix0 + pg * 4;
    f32x4 accp = (f32x4){0.f, 0.f, 0.f, 0.f};
    #pragma unroll
    for (int it = 0; it < 4; ++it) {
        int c = it * 16 + cq;
        f32x4 v = *(const f32x4*)(xb + (size_t)c * NPIX);  // 16-B aligned
        #pragma unroll
        for (int j = 0; j < 4; ++j) {
            accp[j] += v[j] * v[j];
            lds[(pg * 4 + j) * 65 + c] = (short)f2bf(v[j]);
        }
    }
    *(f32x4*)(red4 + tid * 4) = accp;
    __syncthreads();
    const int cs = tid & 63;
    const int quarter = tid >> 6;
    short* xTb = xT + ((size_t)b * XT_PIX + pix0) * 64;
    #pragma unroll
    for (int it = 0; it < 16; ++it) {
        int pixs = quarter * 16 + it;
        xTb[(size_t)pixs * 64 + cs] = lds[pixs * 65 + cs];  // wave writes 128B contiguous
    }
    if (tid < 64) {
        float sacc = 0.f;
        #pragma unroll
        for (int c16 = 0; c16 < 16; ++c16)
            sacc += red4[(c16 * 16 + (tid >> 2)) * 4 + (tid & 3)];
        s[b * NPIX + pix0 + tid] = sacc;
    }
}

// ---------------- fused im2col GEMM + RBF epilogue ----------------
// R8 measured-best structure (A region staged once; tap-major B double-buffered
// via global_load_lds; 8 waves, 128x128 tile; counted-wait + raw-barrier taps).
// NEW: w2 (||window||^2) computed IN-KERNEL from s (3x3 window sum, L2-resident
// scalar loads in the prologue) -> w2_kernel dispatch and its global round-trip
// eliminated. Epilogue: coalesced via [64][132] f32 LDS transpose (reuses lds_a).

#define AS1(p) ((const __attribute__((address_space(1))) void*)(p))
#define AS3(p) ((__attribute__((address_space(3))) void*)(p))

__global__ __launch_bounds__(512, 4) void gemm_rbf(
    const short* __restrict__ xT, const short* __restrict__ wbf,
    const float* __restrict__ s, const float* __restrict__ c2,
    float* __restrict__ out) {
    __shared__ __align__(16) short lds_a[352 * 64];      // 45 KB pixel region, swizzled
    __shared__ __align__(16) short lds_b[2 * 128 * 64];  // 2 x 16 KB per-tap B tiles

    const int mt = blockIdx.x;                 // 0..367
    const int b  = mt / 23;
    const int p0 = (mt % 23) * 128;
    const int n0 = blockIdx.y * 128;

    const int tid  = threadIdx.x;              // 0..511
    const int wave = tid >> 6;                 // 0..7
    const int lane = tid & 63;
    const int r16  = lane & 15;
    const int quad = lane >> 4;
    const int wm = (wave >> 2) * 64;           // 0 or 64
    const int wn = (wave & 3) * 32;            // 0,32,64,96

    const int oh_base  = p0 / WO;
    const int ihw_base = oh_base * WIN_;

    // staging lane mapping: 8 lanes per 128-B row, 16 B per lane.
    // physical chunk (lane&7) of lds row r holds logical chunk (lane&7)^(r&7).
    const int srow = lane >> 3;                // 0..7
    const int scx  = (lane & 7) ^ srow;        // pre-swizzled source chunk

    // ---- A-region staging (ONCE): 352 rows from xT, contiguous pixels ----
    const short* aSrc = xT + ((size_t)b * XT_PIX + ihw_base + srow) * 64 + scx * 8;
    #pragma unroll
    for (int i = 0; i < 6; ++i) {              // 8 waves x 6 x 8 rows, guard at 352
        int rb8 = (wave * 6 + i) * 8;
        if (rb8 < 352)
            __builtin_amdgcn_global_load_lds(AS1(aSrc + (size_t)rb8 * 64),
                                             AS3(lds_a + rb8 * 64), 16, 0, 0);
    }
    // ---- B staging base (tap-major wbf: [tap][o][c]) ----
    const short* gbB = wbf + ((size_t)n0 + wave * 16 + srow) * 64 + scx * 8;
    #pragma unroll
    for (int i = 0; i < 2; ++i)                // tap 0 into buffer 0
        __builtin_amdgcn_global_load_lds(AS1(gbB + (size_t)i * 8 * 64),
                                         AS3(lds_b + (wave * 2 + i) * 512), 16, 0, 0);

    // per-fragment-row pixel index relative to the staged region (pad rows clamped;
    // their D rows are discarded in the store phase)
    int ihw_rel[4];
    #pragma unroll
    for (int ms = 0; ms < 4; ++ms) {
        int p = p0 + wm + ms * 16 + r16;
        if (p > P_PER_B - 1) p = P_PER_B - 1;
        int oh = p / WO, ow = p - oh * WO;
        ihw_rel[ms] = oh * WIN_ + ow - ihw_base;   // 0..221
    }
    const int xq = r16 & 7;                    // B fragment-read swizzle key

    // ---- in-prologue w2 = 3x3 window sum of s (replaces w2_kernel) ----
    const int ecol = tid & 31;                 // f32x4 column within 512-B run
    const int erow = tid >> 5;                 // 0..15
    const int pcol = p0 + ecol * 4;
    const bool pok = (pcol < P_PER_B);         // aligned: P_PER_B % 4 == 0
    f32x4 w2v;
    {
        const int pbase = pok ? pcol : (P_PER_B - 4);
        const float* sb = s + b * NPIX;
        #pragma unroll
        for (int r = 0; r < 4; ++r) {
            int p = pbase + r;
            int oh = p / WO, ow = p - oh * WO;
            const float* sp = sb + oh * WIN_ + ow;
            float a0 = 0.f;
            #pragma unroll
            for (int kh = 0; kh < 3; ++kh)
                #pragma unroll
                for (int kw = 0; kw < 3; ++kw)
                    a0 += sp[kh * WIN_ + kw];   // same summation order as w2_kernel
            w2v[r] = a0;
        }
    }

    f32x4 acc[4][2];
    #pragma unroll
    for (int i = 0; i < 4; ++i)
        #pragma unroll
        for (int j = 0; j < 2; ++j)
            acc[i][j] = (f32x4){0.f, 0.f, 0.f, 0.f};

    constexpr int dtab_l[9] = {0, 1, 2, 56, 57, 58, 112, 113, 114};  // kh*56+kw
    #pragma unroll
    for (int kt = 0; kt < 9; ++kt) {
        // counted-wait + raw barrier (NOT __syncthreads): outstanding loads here
        // were issued one full tap ago -> mostly landed; no forced zero-cover drain.
        asm volatile("s_waitcnt vmcnt(0)" ::: "memory");
        __builtin_amdgcn_s_barrier();
        __builtin_amdgcn_sched_barrier(0);
        if (kt < 8) {                          // issue next tap's B under this tap's MFMAs
            short* dstB = lds_b + ((kt + 1) & 1) * (128 * 64);
            #pragma unroll
            for (int i = 0; i < 2; ++i)
                __builtin_amdgcn_global_load_lds(
                    AS1(gbB + ((size_t)(kt + 1) * OUT_CH + i * 8) * 64),
                    AS3(dstB + (wave * 2 + i) * 512), 16, 0, 0);
        }
        const short* lb = lds_b + (kt & 1) * (128 * 64);
        const int dt = dtab_l[kt];
        __builtin_amdgcn_s_setprio(1);
        #pragma unroll
        for (int ks = 0; ks < 2; ++ks) {
            short8 af[4], bfr[2];
            #pragma unroll
            for (int ms = 0; ms < 4; ++ms) {
                int rl = ihw_rel[ms] + dt;     // staged-region row for this tap
                af[ms] = *(const short8*)(lds_a + rl * 64
                                                + (((ks * 4 + quad) ^ (rl & 7)) * 8));
            }
            #pragma unroll
            for (int ns = 0; ns < 2; ++ns)
                bfr[ns] = *(const short8*)(lb + (wn + ns * 16 + r16) * 64
                                              + (((ks * 4 + quad) ^ xq) * 8));
            #pragma unroll
            for (int ms = 0; ms < 4; ++ms)
                #pragma unroll
                for (int ns = 0; ns < 2; ++ns)
                    acc[ms][ns] = __builtin_amdgcn_mfma_f32_16x16x32_bf16(
                        af[ms], bfr[ns], acc[ms][ns], 0, 0, 0);
        }
        __builtin_amdgcn_s_setprio(0);
    }

    // ---------------- coalesced RBF epilogue via LDS transpose ----------------
    // Two 64-channel chunks; owning waves dump acc into a padded [64][132] f32
    // tile (reusing lds_a); then all 512 threads stream channel-rows out as
    // contiguous 512-B runs.
    float* lf = (float*)lds_a;                 // 64*132*4 = 33.8 KB <= 45 KB
    const int myChunk = (wave >> 1) & 1;       // which 64-ch chunk this wave owns

    #pragma unroll
    for (int sc = 0; sc < 2; ++sc) {
        __syncthreads();                       // lds_a free / prev chunk consumed
        if (myChunk == sc) {
            #pragma unroll
            for (int ms = 0; ms < 4; ++ms) {
                int pl = wm + ms * 16 + quad * 4;
                #pragma unroll
                for (int ns = 0; ns < 2; ++ns) {
                    int od = (wave & 1) * 32 + ns * 16 + r16;   // 0..63 in chunk
                    *(f32x4*)(lf + od * 132 + pl) = acc[ms][ns];
                }
            }
        }
        __syncthreads();
        #pragma unroll
        for (int pass = 0; pass < 4; ++pass) {
            int row = pass * 16 + erow;        // 0..63
            int o   = n0 + sc * 64 + row;
            f32x4 a = *(const f32x4*)(lf + row * 132 + ecol * 4);
            float c2o = c2[o];
            f32x4 v;
            #pragma unroll
            for (int r = 0; r < 4; ++r) {
                float d2 = w2v[r] + c2o - 2.0f * a[r];
                d2 = fmaxf(d2, 1e-12f);
                v[r] = __expf(-0.125f * d2);
            }
            if (pok)
                *(f32x4*)(out + ((size_t)(b * OUT_CH + o)) * P_PER_B + pcol) = v;
        }
    }
}

// ---------------- launch ----------------

extern "C" void kernel_launch(void* const* d_in, const int* in_sizes, int n_in,
                              void* d_out, int out_size, void* d_ws, size_t ws_size,
                              hipStream_t stream) {
    const float* x = (const float*)d_in[0];    // [16,64,56,56]
    const float* w = (const float*)d_in[1];    // [256,576]
    float* out = (float*)d_out;                // [16,256,54,54]

    char* ws = (char*)d_ws;
    const size_t wbf_bytes = (size_t)OUT_CH * KDIM * 2;            // 294,912
    const size_t c2_bytes  = 1024;                                 // OUT_CH*4
    const size_t s_bytes   = (size_t)BATCH * NPIX * 4;             // 200,704
    short* wbf = (short*)ws;
    float* c2  = (float*)(ws + wbf_bytes);
    float* s   = (float*)(ws + wbf_bytes + c2_bytes);
    short* xT  = (short*)(ws + wbf_bytes + c2_bytes + s_bytes);    // 6.68 MB

    hipLaunchKernelGGL(prep_weight, dim3(OUT_CH), dim3(64), 0, stream, w, wbf, c2);
    hipLaunchKernelGGL(transpose_kernel, dim3(16 * 49), dim3(256), 0, stream, x, xT, s);
    hipLaunchKernelGGL(gemm_rbf, dim3(23 * BATCH, OUT_CH / 128), dim3(512), 0, stream,
                       xT, wbf, s, c2, out);
}

// Round 11
// 98.154 us; speedup vs baseline: 1.1491x; 1.0532x over previous
//
#include <hip/hip_runtime.h>
#include <hip/hip_bf16.h>
#include <stdint.h>

// Problem constants
#define BATCH 16
#define IN_CH 64
#define HIN 56
#define WIN_ 56
#define HO 54
#define WO 54
#define P_PER_B (HO*WO)        // 2916
#define P_PAD 2944             // 23 * 128
#define OUT_CH 256
#define KDIM 576               // 64*3*3
#define NPIX (HIN*WIN_)        // 3136
#define XT_PIX 3264            // padded pixel rows per batch (A-region staging overrun)

typedef __attribute__((ext_vector_type(8))) short short8;
typedef __attribute__((ext_vector_type(4))) float f32x4;

__device__ __forceinline__ unsigned short f2bf(float f) {
    unsigned int u = __float_as_uint(f);
    unsigned int r = (u + 0x7fffu + ((u >> 16) & 1u)) >> 16;   // RNE
    return (unsigned short)r;
}

// ---------------- merged prep kernel ----------------
// One dispatch, heterogeneous blocks (saves a launch gap):
//  blocks [0,64):    weight prep — 4 output channels per block (64 lanes each):
//                    bf16-convert into TAP-MAJOR wbf[tap][o][c] + ||w_o||^2.
//  blocks [64,848):  NCHW f32 -> NHWC bf16 transpose (64 pix x 64 ch) with
//                    float4 loads + fused per-pixel channel square-sum s[b,pix].
__global__ __launch_bounds__(256) void prep_merged(
    const float* __restrict__ w, short* __restrict__ wbf, float* __restrict__ c2,
    const float* __restrict__ x, short* __restrict__ xT, float* __restrict__ s) {
    __shared__ short lds[64 * 65];
    __shared__ float red4[256 * 4];            // [cq][pixgrp][4]

    if (blockIdx.x < 64) {
        // ---- weight prep: o = blockIdx.x*4 + quarter ----
        const int o = blockIdx.x * 4 + (threadIdx.x >> 6);
        const int lane = threadIdx.x & 63;
        float sw = 0.f;
        #pragma unroll
        for (int j = 0; j < 9; ++j) {          // 576 = 9*64
            int k = j * 64 + lane;             // original k = c*9 + tap
            int c = k / 9, tap = k % 9;
            float v = w[o * KDIM + k];
            sw += v * v;
            ((unsigned short*)wbf)[((size_t)tap * OUT_CH + o) * 64 + c] = f2bf(v);
        }
        #pragma unroll
        for (int off = 32; off > 0; off >>= 1) sw += __shfl_down(sw, off);
        if (lane == 0) c2[o] = sw;
        return;
    }

    const int blk  = blockIdx.x - 64;          // 0..783
    const int b    = blk / 49;
    const int pix0 = (blk % 49) * 64;
    const int tid  = threadIdx.x;
    const int cq = tid >> 4;                   // 0..15 channel group
    const int pg = tid & 15;                   // 0..15 pixel group (4 pix each)
    const float* xb = x + (size_t)b * IN_CH * NPIX + pix0 + pg * 4;
    f32x4 accp = (f32x4){0.f, 0.f, 0.f, 0.f};
    #pragma unroll
    for (int it = 0; it < 4; ++it) {
        int c = it * 16 + cq;
        f32x4 v = *(const f32x4*)(xb + (size_t)c * NPIX);  // 16-B aligned
        #pragma unroll
        for (int j = 0; j < 4; ++j) {
            accp[j] += v[j] * v[j];
            lds[(pg * 4 + j) * 65 + c] = (short)f2bf(v[j]);
        }
    }
    *(f32x4*)(red4 + tid * 4) = accp;
    __syncthreads();
    const int cs = tid & 63;
    const int quarter = tid >> 6;
    short* xTb = xT + ((size_t)b * XT_PIX + pix0) * 64;
    #pragma unroll
    for (int it = 0; it < 16; ++it) {
        int pixs = quarter * 16 + it;
        xTb[(size_t)pixs * 64 + cs] = lds[pixs * 65 + cs];  // wave writes 128B contiguous
    }
    if (tid < 64) {
        float sacc = 0.f;
        #pragma unroll
        for (int c16 = 0; c16 < 16; ++c16)
            sacc += red4[(c16 * 16 + (tid >> 2)) * 4 + (tid & 3)];
        s[b * NPIX + pix0 + tid] = sacc;
    }
}

// ---------------- fused im2col GEMM + RBF epilogue ----------------
// R10 measured-best structure, unchanged compute; NEW: XCD-chunked bijective
// blockIdx.x swizzle (368 = 8*46). Dispatch id = y*368 + x, XCD = id%8;
// swizzled mt = (x&7)*46 + (x>>3) puts consecutive m-tiles (overlapping A
// pixel-regions + s windows) on the SAME XCD L2, and both n-tiles of an
// m-tile on the same XCD (368%8==0).

#define AS1(p) ((const __attribute__((address_space(1))) void*)(p))
#define AS3(p) ((__attribute__((address_space(3))) void*)(p))

__global__ __launch_bounds__(512, 4) void gemm_rbf(
    const short* __restrict__ xT, const short* __restrict__ wbf,
    const float* __restrict__ s, const float* __restrict__ c2,
    float* __restrict__ out) {
    __shared__ __align__(16) short lds_a[352 * 64];      // 45 KB pixel region, swizzled
    __shared__ __align__(16) short lds_b[2 * 128 * 64];  // 2 x 16 KB per-tap B tiles

    const int bx = blockIdx.x;                 // 0..367
    const int mt = (bx & 7) * 46 + (bx >> 3);  // XCD-chunked, bijective
    const int b  = mt / 23;
    const int p0 = (mt % 23) * 128;
    const int n0 = blockIdx.y * 128;

    const int tid  = threadIdx.x;              // 0..511
    const int wave = tid >> 6;                 // 0..7
    const int lane = tid & 63;
    const int r16  = lane & 15;
    const int quad = lane >> 4;
    const int wm = (wave >> 2) * 64;           // 0 or 64
    const int wn = (wave & 3) * 32;            // 0,32,64,96

    const int oh_base  = p0 / WO;
    const int ihw_base = oh_base * WIN_;

    // staging lane mapping: 8 lanes per 128-B row, 16 B per lane.
    // physical chunk (lane&7) of lds row r holds logical chunk (lane&7)^(r&7).
    const int srow = lane >> 3;                // 0..7
    const int scx  = (lane & 7) ^ srow;        // pre-swizzled source chunk

    // ---- A-region staging (ONCE): 352 rows from xT, contiguous pixels ----
    const short* aSrc = xT + ((size_t)b * XT_PIX + ihw_base + srow) * 64 + scx * 8;
    #pragma unroll
    for (int i = 0; i < 6; ++i) {              // 8 waves x 6 x 8 rows, guard at 352
        int rb8 = (wave * 6 + i) * 8;
        if (rb8 < 352)
            __builtin_amdgcn_global_load_lds(AS1(aSrc + (size_t)rb8 * 64),
                                             AS3(lds_a + rb8 * 64), 16, 0, 0);
    }
    // ---- B staging base (tap-major wbf: [tap][o][c]) ----
    const short* gbB = wbf + ((size_t)n0 + wave * 16 + srow) * 64 + scx * 8;
    #pragma unroll
    for (int i = 0; i < 2; ++i)                // tap 0 into buffer 0
        __builtin_amdgcn_global_load_lds(AS1(gbB + (size_t)i * 8 * 64),
                                         AS3(lds_b + (wave * 2 + i) * 512), 16, 0, 0);

    // per-fragment-row pixel index relative to the staged region (pad rows clamped;
    // their D rows are discarded in the store phase)
    int ihw_rel[4];
    #pragma unroll
    for (int ms = 0; ms < 4; ++ms) {
        int p = p0 + wm + ms * 16 + r16;
        if (p > P_PER_B - 1) p = P_PER_B - 1;
        int oh = p / WO, ow = p - oh * WO;
        ihw_rel[ms] = oh * WIN_ + ow - ihw_base;   // 0..221
    }
    const int xq = r16 & 7;                    // B fragment-read swizzle key

    // ---- in-prologue w2 = 3x3 window sum of s (replaces w2_kernel) ----
    const int ecol = tid & 31;                 // f32x4 column within 512-B run
    const int erow = tid >> 5;                 // 0..15
    const int pcol = p0 + ecol * 4;
    const bool pok = (pcol < P_PER_B);         // aligned: P_PER_B % 4 == 0
    f32x4 w2v;
    {
        const int pbase = pok ? pcol : (P_PER_B - 4);
        const float* sb = s + b * NPIX;
        #pragma unroll
        for (int r = 0; r < 4; ++r) {
            int p = pbase + r;
            int oh = p / WO, ow = p - oh * WO;
            const float* sp = sb + oh * WIN_ + ow;
            float a0 = 0.f;
            #pragma unroll
            for (int kh = 0; kh < 3; ++kh)
                #pragma unroll
                for (int kw = 0; kw < 3; ++kw)
                    a0 += sp[kh * WIN_ + kw];   // same summation order as w2_kernel
            w2v[r] = a0;
        }
    }

    f32x4 acc[4][2];
    #pragma unroll
    for (int i = 0; i < 4; ++i)
        #pragma unroll
        for (int j = 0; j < 2; ++j)
            acc[i][j] = (f32x4){0.f, 0.f, 0.f, 0.f};

    constexpr int dtab_l[9] = {0, 1, 2, 56, 57, 58, 112, 113, 114};  // kh*56+kw
    #pragma unroll
    for (int kt = 0; kt < 9; ++kt) {
        // counted-wait + raw barrier (NOT __syncthreads): outstanding loads here
        // were issued one full tap ago -> mostly landed; no forced zero-cover drain.
        asm volatile("s_waitcnt vmcnt(0)" ::: "memory");
        __builtin_amdgcn_s_barrier();
        __builtin_amdgcn_sched_barrier(0);
        if (kt < 8) {                          // issue next tap's B under this tap's MFMAs
            short* dstB = lds_b + ((kt + 1) & 1) * (128 * 64);
            #pragma unroll
            for (int i = 0; i < 2; ++i)
                __builtin_amdgcn_global_load_lds(
                    AS1(gbB + ((size_t)(kt + 1) * OUT_CH + i * 8) * 64),
                    AS3(dstB + (wave * 2 + i) * 512), 16, 0, 0);
        }
        const short* lb = lds_b + (kt & 1) * (128 * 64);
        const int dt = dtab_l[kt];
        __builtin_amdgcn_s_setprio(1);
        #pragma unroll
        for (int ks = 0; ks < 2; ++ks) {
            short8 af[4], bfr[2];
            #pragma unroll
            for (int ms = 0; ms < 4; ++ms) {
                int rl = ihw_rel[ms] + dt;     // staged-region row for this tap
                af[ms] = *(const short8*)(lds_a + rl * 64
                                                + (((ks * 4 + quad) ^ (rl & 7)) * 8));
            }
            #pragma unroll
            for (int ns = 0; ns < 2; ++ns)
                bfr[ns] = *(const short8*)(lb + (wn + ns * 16 + r16) * 64
                                              + (((ks * 4 + quad) ^ xq) * 8));
            #pragma unroll
            for (int ms = 0; ms < 4; ++ms)
                #pragma unroll
                for (int ns = 0; ns < 2; ++ns)
                    acc[ms][ns] = __builtin_amdgcn_mfma_f32_16x16x32_bf16(
                        af[ms], bfr[ns], acc[ms][ns], 0, 0, 0);
        }
        __builtin_amdgcn_s_setprio(0);
    }

    // ---------------- coalesced RBF epilogue via LDS transpose ----------------
    // Two 64-channel chunks; owning waves dump acc into a padded [64][132] f32
    // tile (reusing lds_a); then all 512 threads stream channel-rows out as
    // contiguous 512-B runs.
    float* lf = (float*)lds_a;                 // 64*132*4 = 33.8 KB <= 45 KB
    const int myChunk = (wave >> 1) & 1;       // which 64-ch chunk this wave owns

    #pragma unroll
    for (int sc = 0; sc < 2; ++sc) {
        __syncthreads();                       // lds_a free / prev chunk consumed
        if (myChunk == sc) {
            #pragma unroll
            for (int ms = 0; ms < 4; ++ms) {
                int pl = wm + ms * 16 + quad * 4;
                #pragma unroll
                for (int ns = 0; ns < 2; ++ns) {
                    int od = (wave & 1) * 32 + ns * 16 + r16;   // 0..63 in chunk
                    *(f32x4*)(lf + od * 132 + pl) = acc[ms][ns];
                }
            }
        }
        __syncthreads();
        #pragma unroll
        for (int pass = 0; pass < 4; ++pass) {
            int row = pass * 16 + erow;        // 0..63
            int o   = n0 + sc * 64 + row;
            f32x4 a = *(const f32x4*)(lf + row * 132 + ecol * 4);
            float c2o = c2[o];
            f32x4 v;
            #pragma unroll
            for (int r = 0; r < 4; ++r) {
                float d2 = w2v[r] + c2o - 2.0f * a[r];
                d2 = fmaxf(d2, 1e-12f);
                v[r] = __expf(-0.125f * d2);
            }
            if (pok)
                *(f32x4*)(out + ((size_t)(b * OUT_CH + o)) * P_PER_B + pcol) = v;
        }
    }
}

// ---------------- launch ----------------

extern "C" void kernel_launch(void* const* d_in, const int* in_sizes, int n_in,
                              void* d_out, int out_size, void* d_ws, size_t ws_size,
                              hipStream_t stream) {
    const float* x = (const float*)d_in[0];    // [16,64,56,56]
    const float* w = (const float*)d_in[1];    // [256,576]
    float* out = (float*)d_out;                // [16,256,54,54]

    char* ws = (char*)d_ws;
    const size_t wbf_bytes = (size_t)OUT_CH * KDIM * 2;            // 294,912
    const size_t c2_bytes  = 1024;                                 // OUT_CH*4
    const size_t s_bytes   = (size_t)BATCH * NPIX * 4;             // 200,704
    short* wbf = (short*)ws;
    float* c2  = (float*)(ws + wbf_bytes);
    float* s   = (float*)(ws + wbf_bytes + c2_bytes);
    short* xT  = (short*)(ws + wbf_bytes + c2_bytes + s_bytes);    // 6.68 MB

    hipLaunchKernelGGL(prep_merged, dim3(64 + 16 * 49), dim3(256), 0, stream,
                       w, wbf, c2, x, xT, s);
    hipLaunchKernelGGL(gemm_rbf, dim3(23 * BATCH, OUT_CH / 128), dim3(512), 0, stream,
                       xT, wbf, s, c2, out);
}